// Round 7
// baseline (194.905 us; speedup 1.0000x reference)
//
#include <hip/hip_runtime.h>

// Gray-Scott PDE residual, 8-row y-tiles x 2 x-halves, LDS-staged stencil,
// dist-2 register prefetch, one output row per thread.
//   in  : (T=20, B=8, C=3, H=256, W=256) fp32; u = ch1, v = ch2
//   out : [f_u | f_v], each (20,8,1,252,252) fp32
//
// R7 vs R6: R6 counters (first direct capture): VALUBusy 5.7%, HBM 17%,
// Occupancy 11% (4 waves/CU) -> NOTHING saturated; latency/serialization-
// bound. FETCH=42MB shows the input is L3-resident; traffic is cheap, waves
// are scarce. R7 keeps R6's 1.5x read amplification but splits each tile
// into two x-halves: 512 blocks = 2 blocks/CU = 8 waves/CU (R5 residency),
// 25 KB LDS dbuf/block, all staging loads 16B-aligned (halves start at
// col 0 / col 124), one output row x 4 cols per thread.

#define T_OUT (8 * 252 * 252)

typedef float vf4 __attribute__((ext_vector_type(4)));

static __device__ __forceinline__ vf4 lds4u(const float* p) {
    vf4 v;
    __builtin_memcpy(&v, p, 16);   // 8B-aligned LDS 16B read
    return v;
}

struct GSRow {
    vf4 u_cm2, u_cm1, u_cc, u_lm1, u_l0;
    vf4 v_cm2, v_cm1, v_cc, v_lm1, v_l0;
};

#define GS_INT(c) { \
    float ut = (ucn.c - s.u_cm1.c) * hdt; \
    float vt = (vcn.c - s.v_cm1.c) * hdt; \
    float uvv = s.u_cc.c * s.v_cc.c * s.v_cc.c; \
    fu.c = Du * s.u_lm1.c - uvv + fR * (1.0f - s.u_cc.c) - ut; \
    fv.c = Dv * s.v_lm1.c + uvv - (fR + kR) * s.v_cc.c - vt; }

#define GS_T0(c) { \
    float ut = (-1.5f * s.u_cm1.c + 2.0f * s.u_cc.c - 0.5f * ucn.c) * inv_dt; \
    float vt = (-1.5f * s.v_cm1.c + 2.0f * s.v_cc.c - 0.5f * vcn.c) * inv_dt; \
    float uvv = s.u_cm1.c * s.v_cm1.c * s.v_cm1.c; \
    fu.c = Du * s.u_l0.c - uvv + fR * (1.0f - s.u_cm1.c) - ut; \
    fv.c = Dv * s.v_l0.c + uvv - (fR + kR) * s.v_cm1.c - vt; }

#define GS_TN(c) { \
    float ut = (0.5f * s.u_cm2.c - 2.0f * s.u_cm1.c + 1.5f * s.u_cc.c) * inv_dt; \
    float vt = (0.5f * s.v_cm2.c - 2.0f * s.v_cm1.c + 1.5f * s.v_cc.c) * inv_dt; \
    float uvv = s.u_cc.c * s.v_cc.c * s.v_cc.c; \
    fu.c = Du * s.u_lm1.c - uvv + fR * (1.0f - s.u_cc.c) - ut; \
    fv.c = Dv * s.v_lm1.c + uvv - (fR + kR) * s.v_cc.c - vt; }

// One output row's GS update at time t.
// L rows: u = 0..11 (tile rows y0..y0+11), v = 12..23.
// Output row y0+R uses u LDS rows R..R+4 (center R+2), v rows R+12..R+16.
// a0 = 16B-aligned LDS col of the leftmost center-row element.
static __device__ __forceinline__ void gs_step(
    const float (*L)[132], int R, int a0, int t, GSRow& s,
    float* __restrict__ outu, float* __restrict__ outv)
{
    const float C1 = 4.0f / 3.0f, C2 = 1.0f / 12.0f;
    const float inv_dx2 = 1.0f / (0.15625f * 0.15625f);   // DX = 20/128
    const float inv_dt  = 20.0f;                          // 1/DT
    const float hdt     = 10.0f;                          // 1/(2 DT)
    const float Du = 0.16f, Dv = 0.08f, fR = 0.06f, kR = 0.062f;

    vf4 uL  = *(const vf4*)&L[R + 2][a0];
    vf4 uR  = *(const vf4*)&L[R + 2][a0 + 4];
    vf4 um1 = lds4u(&L[R + 1][a0 + 2]);
    vf4 up1 = lds4u(&L[R + 3][a0 + 2]);
    vf4 um2 = lds4u(&L[R    ][a0 + 2]);
    vf4 up2 = lds4u(&L[R + 4][a0 + 2]);

    vf4 vL  = *(const vf4*)&L[R + 14][a0];
    vf4 vR  = *(const vf4*)&L[R + 14][a0 + 4];
    vf4 vm1 = lds4u(&L[R + 13][a0 + 2]);
    vf4 vp1 = lds4u(&L[R + 15][a0 + 2]);
    vf4 vm2 = lds4u(&L[R + 12][a0 + 2]);
    vf4 vp2 = lds4u(&L[R + 16][a0 + 2]);

    vf4 lu, lv;
    lu.x = (C1*(uL.y + uL.w + um1.x + up1.x) - C2*(uL.x + uR.x + um2.x + up2.x) - 5.0f*uL.z) * inv_dx2;
    lu.y = (C1*(uL.z + uR.x + um1.y + up1.y) - C2*(uL.y + uR.y + um2.y + up2.y) - 5.0f*uL.w) * inv_dx2;
    lu.z = (C1*(uL.w + uR.y + um1.z + up1.z) - C2*(uL.z + uR.z + um2.z + up2.z) - 5.0f*uR.x) * inv_dx2;
    lu.w = (C1*(uR.x + uR.z + um1.w + up1.w) - C2*(uL.w + uR.w + um2.w + up2.w) - 5.0f*uR.y) * inv_dx2;
    lv.x = (C1*(vL.y + vL.w + vm1.x + vp1.x) - C2*(vL.x + vR.x + vm2.x + vp2.x) - 5.0f*vL.z) * inv_dx2;
    lv.y = (C1*(vL.z + vR.x + vm1.y + vp1.y) - C2*(vL.y + vR.y + vm2.y + vp2.y) - 5.0f*vL.w) * inv_dx2;
    lv.z = (C1*(vL.w + vR.y + vm1.z + vp1.z) - C2*(vL.z + vR.z + vm2.z + vp2.z) - 5.0f*vR.x) * inv_dx2;
    lv.w = (C1*(vR.x + vR.z + vm1.w + vp1.w) - C2*(vL.w + vR.w + vm2.w + vp2.w) - 5.0f*vR.y) * inv_dx2;

    vf4 ucn = {uL.z, uL.w, uR.x, uR.y};   // centers at t
    vf4 vcn = {vL.z, vL.w, vR.x, vR.y};

    if (t == 0) { s.u_l0 = lu; s.v_l0 = lv; }

    if (t == 2) {
        // emit t=0 one-sided: c0=cm1, c1=cc, c2=ucn, lap=l0
        vf4 fu, fv;
        GS_T0(x); GS_T0(y); GS_T0(z); GS_T0(w);
        __builtin_nontemporal_store(fu, (vf4*)(outu));
        __builtin_nontemporal_store(fv, (vf4*)(outv));
    }

    if (t >= 2) {
        // emit t-1 interior: center=cc, u_t=(c_t - c_{t-2})/(2DT), lap=lm1
        vf4 fu, fv;
        GS_INT(x); GS_INT(y); GS_INT(z); GS_INT(w);
        __builtin_nontemporal_store(fu, (vf4*)(outu + (size_t)(t - 1) * T_OUT));
        __builtin_nontemporal_store(fv, (vf4*)(outv + (size_t)(t - 1) * T_OUT));
    }

    s.u_cm2 = s.u_cm1; s.u_cm1 = s.u_cc; s.u_cc = ucn; s.u_lm1 = lu;
    s.v_cm2 = s.v_cm1; s.v_cm1 = s.v_cc; s.v_cc = vcn; s.v_lm1 = lv;
}

__global__ __launch_bounds__(256) void gs_loss_kernel(
    const float* __restrict__ in, float* __restrict__ out)
{
    // [buf][row][col]: rows 0..11 = u rows y0..y0+11, rows 12..23 = v.
    // 2 * 24 * 132 * 4 B = 25.3 KB.
    __shared__ float lds[2][24][132];

    const int tid = threadIdx.x;

    const int b     = blockIdx.x & 7;          // batch -> XCD pinning
    const int xh    = (blockIdx.x >> 3) & 1;   // x-half
    const int ytile = blockIdx.x >> 4;         // 0..31
    const int y0    = ytile * 8;               // 0..248 (tile 31 ragged)

    const int planeStride = 256 * 256;
    const int bStride     = 3 * planeStride;
    const int tStride     = 24 * planeStride;

    const float* base0 = in + (size_t)b * bStride + planeStride;  // u, t=0

    // ---- staging slots: 24 rows x 33 aligned dwordx4 = 792 vec4 units ----
    // slot i covers unit idx = tid + 256*i; i=0..2 always, i=3 for tid<24.
    const bool s3 = (tid < 24);
    int goffs[4], loffs[4];
#pragma unroll
    for (int i = 0; i < 4; ++i) {
        int idx = tid + 256 * i;
        if (idx >= 792) idx = 791;             // clamp; slot 3 masked by s3
        int r  = idx / 33;                     // LDS row 0..23
        int g  = idx - r * 33;                 // vec4 group 0..32
        int pr = (r < 12) ? r : r - 12;        // row within plane tile
        int pl = (r < 12) ? 0 : 1;             // 0 = u, 1 = v
        int gy = y0 + pr; if (gy > 255) gy = 255;   // ragged tile 31 clamp
        goffs[i] = pl * planeStride + gy * 256 + xh * 124 + g * 4;
        loffs[i] = r * 132 + g * 4;
    }

    // ---- compute role: one output row, 4 cols ----
    const int R  = tid >> 5;                   // 0..7
    const int cg = tid & 31;                   // col group
    const int c0 = xh * 128 + cg * 4;          // output col
    const int a0 = cg * 4 + 4 * xh;            // aligned LDS col of center row
    const bool act = (c0 <= 248) && (y0 + R < 252);

    const int total = 20 * T_OUT;
    float* outu = out + ((size_t)b * 252 + (y0 + R)) * 252 + c0;
    float* outv = outu + total;

    GSRow s{};

    vf4 sA0, sA1, sA2, sA3;   // prefetch set A (even t)
    vf4 sB0, sB1, sB2, sB3;   // prefetch set B (odd t)

#define ISSUE_A(t) { const float* bt = base0 + (size_t)(t) * tStride; \
    sA0 = *(const vf4*)(bt + goffs[0]); \
    sA1 = *(const vf4*)(bt + goffs[1]); \
    sA2 = *(const vf4*)(bt + goffs[2]); \
    if (s3) sA3 = *(const vf4*)(bt + goffs[3]); }
#define ISSUE_B(t) { const float* bt = base0 + (size_t)(t) * tStride; \
    sB0 = *(const vf4*)(bt + goffs[0]); \
    sB1 = *(const vf4*)(bt + goffs[1]); \
    sB2 = *(const vf4*)(bt + goffs[2]); \
    if (s3) sB3 = *(const vf4*)(bt + goffs[3]); }

    ISSUE_A(0);
    ISSUE_B(1);

#pragma unroll
    for (int t = 0; t < 20; ++t) {
        float* Lf = &lds[t & 1][0][0];

        // stage t (compiler emits the partial vmcnt for this set's arrival)
        if ((t & 1) == 0) {
            *(vf4*)(Lf + loffs[0]) = sA0;
            *(vf4*)(Lf + loffs[1]) = sA1;
            *(vf4*)(Lf + loffs[2]) = sA2;
            if (s3) *(vf4*)(Lf + loffs[3]) = sA3;
        } else {
            *(vf4*)(Lf + loffs[0]) = sB0;
            *(vf4*)(Lf + loffs[1]) = sB1;
            *(vf4*)(Lf + loffs[2]) = sB2;
            if (s3) *(vf4*)(Lf + loffs[3]) = sB3;
        }

        __syncthreads();
        // One barrier per t is safe with the double buffer: a wave writing
        // lds[(t+2)&1] has passed barrier(t+1), which implies every wave
        // finished compute(t) on that same buffer.

        // prefetch t+2 into the register set just freed (2-iteration cover)
        if (t + 2 < 20) {
            if ((t & 1) == 0) { ISSUE_A(t + 2); } else { ISSUE_B(t + 2); }
        }

        if (act) {
            gs_step(lds[t & 1], R, a0, t, s, outu, outv);
        }
    }

    if (act) {
        // emit t=19 one-sided: c17=cm2, c18=cm1, c19=cc, lap19=lm1
        const float inv_dt = 20.0f;
        const float Du = 0.16f, Dv = 0.08f, fR = 0.06f, kR = 0.062f;
        vf4 fu, fv;
        GS_TN(x); GS_TN(y); GS_TN(z); GS_TN(w);
        __builtin_nontemporal_store(fu, (vf4*)(outu + (size_t)19 * T_OUT));
        __builtin_nontemporal_store(fv, (vf4*)(outv + (size_t)19 * T_OUT));
    }
}

extern "C" void kernel_launch(void* const* d_in, const int* in_sizes, int n_in,
                              void* d_out, int out_size, void* d_ws, size_t ws_size,
                              hipStream_t stream) {
    const float* in = (const float*)d_in[0];
    float* out = (float*)d_out;

    // 8 b * 2 x-halves * 32 y-tiles = 512 blocks of 256 threads
    // (2 blocks/CU = 8 waves/CU, 25.3 KB LDS each)
    gs_loss_kernel<<<8 * 2 * 32, 256, 0, stream>>>(in, out);
}